// Round 4
// baseline (271.274 us; speedup 1.0000x reference)
//
#include <hip/hip_runtime.h>
#include <stdint.h>

// MultiHeadedAttention: B=2,S=2048,D=1024,H=16,HD=64
// R4: attn = 32x32x16 MFMA, in-register P (cvt_pk_bf16 + permlane32_swap),
// no LDS / no barriers, direct-global K/V/mask frags, bf16 mask (pre *log2e),
// max-free softmax, K reg-prefetch. 4-wave blocks = 2 qtiles x 2 heads (L1 share).
// Workspace: 0 qb/vT(reuse), 8 kb/x(reuse), 16 vb/mb0(reuse), 24 w3(6MB),
//            30 wo(2MB), 32 qh, 40 kh, 48 vh/mb1(reuse)  (total 56MB)

typedef __bf16 bf16x8 __attribute__((ext_vector_type(8)));
typedef __bf16 bf16x4 __attribute__((ext_vector_type(4)));
typedef float f32x4 __attribute__((ext_vector_type(4)));
typedef float f32x16 __attribute__((ext_vector_type(16)));
typedef unsigned u32x4 __attribute__((ext_vector_type(4)));

static constexpr float L2E  = 1.4426950408889634f;
static constexpr float QSCL = 0.18033688011112042f;   // 0.125 * log2(e)
static constexpr float GELC = -2.4554669595930157f;   // -1.702 * log2(e)

__device__ __forceinline__ void async_load16(const void* g, void* l) {
    __builtin_amdgcn_global_load_lds(
        (const __attribute__((address_space(1))) unsigned int*)(uintptr_t)g,
        (__attribute__((address_space(3))) unsigned int*)(unsigned int)(uintptr_t)l,
        16, 0, 0);
}

template <int ROWS>
__device__ __forceinline__ void stage_tile(const __bf16* g, int ld, __bf16* lds, int tid) {
#pragma unroll
    for (int r = 0; r < ROWS / 32; ++r) {
        int p = r * 4096 + tid * 16;
        int row = p >> 7;
        int kbp = p & 127;
        int kbl = kbp ^ ((row & 7) << 4);
        async_load16((const char*)(g + (size_t)row * ld) + kbl,
                     (char*)lds + (p & ~1023));
    }
}

__device__ __forceinline__ bf16x8 lds_frag(const __bf16* base, int row, int kb) {
    return *(const bf16x8*)((const char*)base + (row << 7) + (kb ^ ((row & 7) << 4)));
}

__device__ __forceinline__ unsigned cvtpk(float a, float b) {
    unsigned d;
    asm("v_cvt_pk_bf16_f32 %0, %1, %2" : "=v"(d) : "v"(a), "v"(b));
    return d;
}
__device__ __forceinline__ void pswap(unsigned& a, unsigned& b) {
    asm("v_permlane32_swap_b32 %0, %1" : "+v"(a), "+v"(b));
}

// ---------------- prep kernels ----------------

__global__ __launch_bounds__(256) void cvt3_kernel(const float* __restrict__ q,
                                                   const float* __restrict__ k,
                                                   const float* __restrict__ v,
                                                   __bf16* __restrict__ qb,
                                                   __bf16* __restrict__ kb,
                                                   __bf16* __restrict__ vb) {
    int z = blockIdx.y;
    const float* src = z == 0 ? q : (z == 1 ? k : v);
    __bf16* dst = z == 0 ? qb : (z == 1 ? kb : vb);
    int i = blockIdx.x * 256 + threadIdx.x;
    f32x4 val = ((const f32x4*)src)[i];
    bf16x4 o;
    o[0] = (__bf16)val[0]; o[1] = (__bf16)val[1];
    o[2] = (__bf16)val[2]; o[3] = (__bf16)val[3];
    ((bf16x4*)dst)[i] = o;
}

// mask f32 -> bf16 pre-scaled by log2(e); split per batch into mb[b]
__global__ __launch_bounds__(256) void mask_prep(const float* __restrict__ m,
                                                 __bf16* __restrict__ mb0,
                                                 __bf16* __restrict__ mb1) {
    int b = blockIdx.y;
    const f32x4* src = (const f32x4*)(m + (size_t)b * 4194304);
    __bf16* dst = b ? mb1 : mb0;
    int i = blockIdx.x * 256 + threadIdx.x;
    f32x4 val = src[i];
    bf16x4 o;
    o[0] = (__bf16)(val[0] * L2E); o[1] = (__bf16)(val[1] * L2E);
    o[2] = (__bf16)(val[2] * L2E); o[3] = (__bf16)(val[3] * L2E);
    ((bf16x4*)dst)[i] = o;
}

__global__ __launch_bounds__(256) void pack_wqkv(const float* __restrict__ Wq,
                                                 const float* __restrict__ Wk,
                                                 const float* __restrict__ Wv,
                                                 __bf16* __restrict__ out) {
    __shared__ __bf16 T[64][72];
    int tid = threadIdx.x;
    int k0 = blockIdx.x * 64, h = blockIdx.y, z = blockIdx.z;
    const float* W = z == 0 ? Wq : (z == 1 ? Wk : Wv);
#pragma unroll
    for (int it = 0; it < 4; ++it) {
        int idx = it * 1024 + tid * 4;
        int r = idx >> 6, e = idx & 63;
        f32x4 val = *(const f32x4*)(W + ((size_t)h * 1024 + k0 + r) * 64 + e);
#pragma unroll
        for (int j = 0; j < 4; ++j) T[r][e + j] = (__bf16)val[j];
    }
    __syncthreads();
    int e2 = tid >> 2, kc = (tid & 3) * 16;
    bf16x8 o0, o1;
#pragma unroll
    for (int i = 0; i < 8; ++i) { o0[i] = T[kc + i][e2]; o1[i] = T[kc + 8 + i][e2]; }
    __bf16* dst = out + ((size_t)z << 20) + (size_t)(h * 64 + e2) * 1024 + k0 + kc;
    *(bf16x8*)dst = o0;
    *(bf16x8*)(dst + 8) = o1;
}

__global__ __launch_bounds__(256) void pack_wo(const float* __restrict__ Wo,
                                               __bf16* __restrict__ out) {
    __shared__ __bf16 T[64][72];
    int tid = threadIdx.x;
    int k0 = blockIdx.x * 64, n0 = blockIdx.y * 64;
#pragma unroll
    for (int it = 0; it < 4; ++it) {
        int idx = it * 1024 + tid * 4;
        int r = idx >> 6, e = idx & 63;
        f32x4 val = *(const f32x4*)(Wo + (size_t)(k0 + r) * 1024 + n0 + e);
#pragma unroll
        for (int j = 0; j < 4; ++j) T[r][e + j] = (__bf16)val[j];
    }
    __syncthreads();
    int e2 = tid >> 2, kc = (tid & 3) * 16;
    bf16x8 o0, o1;
#pragma unroll
    for (int i = 0; i < 8; ++i) { o0[i] = T[kc + i][e2]; o1[i] = T[kc + 8 + i][e2]; }
    __bf16* dst = out + (size_t)(n0 + e2) * 1024 + k0 + kc;
    *(bf16x8*)dst = o0;
    *(bf16x8*)(dst + 8) = o1;
}

// vh [B,S,D] bf16 -> vT [B,H,HD,S] bf16
__global__ __launch_bounds__(256) void vtrans(const __bf16* __restrict__ vh,
                                              __bf16* __restrict__ vT) {
    __shared__ __bf16 T[64][72];
    int tid = threadIdx.x;
    int s0 = blockIdx.x * 64, bh = blockIdx.y, b = bh >> 4, h = bh & 15;
#pragma unroll
    for (int it = 0; it < 2; ++it) {
        int idx = it * 2048 + tid * 8;
        int r = idx >> 6, e0 = idx & 63;
        bf16x8 val = *(const bf16x8*)(vh + ((size_t)b * 2048 + s0 + r) * 1024 + h * 64 + e0);
#pragma unroll
        for (int j = 0; j < 8; ++j) T[r][e0 + j] = val[j];
    }
    __syncthreads();
    int e = tid >> 2, sc = (tid & 3) * 16;
    bf16x8 o0, o1;
#pragma unroll
    for (int i = 0; i < 8; ++i) { o0[i] = T[sc + i][e]; o1[i] = T[sc + 8 + i][e]; }
    __bf16* dst = vT + ((size_t)bh * 64 + e) * 2048 + s0 + sc;
    *(bf16x8*)dst = o0;
    *(bf16x8*)(dst + 8) = o1;
}

// ---------------- fused QKV GEMM ----------------
__global__ __launch_bounds__(256) void gemm_qkv(
    const __bf16* __restrict__ qb, const __bf16* __restrict__ kb,
    const __bf16* __restrict__ vb, const __bf16* __restrict__ w3,
    const float* __restrict__ bq, const float* __restrict__ bk,
    const float* __restrict__ bv,
    __bf16* __restrict__ qo, __bf16* __restrict__ ko, __bf16* __restrict__ vo) {
    __shared__ __bf16 As[128 * 64];
    __shared__ __bf16 Bs[128 * 64];
    int z = blockIdx.z;
    const __bf16* A = z == 0 ? qb : (z == 1 ? kb : vb);
    const __bf16* Bt = w3 + ((size_t)z << 20);
    const float* bias = z == 0 ? bq : (z == 1 ? bk : bv);
    __bf16* dst = z == 0 ? qo : (z == 1 ? ko : vo);
    float sc = z == 0 ? QSCL : 1.0f;

    int tid = threadIdx.x;
    int w = tid >> 6, lane = tid & 63, lg = lane >> 4, lr = lane & 15;
    int wr = (w >> 1) * 64, wc = (w & 1) * 64;
    int m0 = blockIdx.y * 128, n0 = blockIdx.x * 128;
    f32x4 acc[4][4] = {};
    for (int k0 = 0; k0 < 1024; k0 += 64) {
        __syncthreads();
        stage_tile<128>(A + (size_t)m0 * 1024 + k0, 1024, As, tid);
        stage_tile<128>(Bt + (size_t)n0 * 1024 + k0, 1024, Bs, tid);
        __syncthreads();
#pragma unroll
        for (int kk = 0; kk < 2; ++kk) {
            bf16x8 af[4], bfr[4];
#pragma unroll
            for (int t = 0; t < 4; ++t) {
                af[t] = lds_frag(As, wr + t * 16 + lr, lg * 16 + kk * 64);
                bfr[t] = lds_frag(Bs, wc + t * 16 + lr, lg * 16 + kk * 64);
            }
#pragma unroll
            for (int i = 0; i < 4; ++i)
#pragma unroll
                for (int j = 0; j < 4; ++j)
                    acc[i][j] = __builtin_amdgcn_mfma_f32_16x16x32_bf16(
                        af[i], bfr[j], acc[i][j], 0, 0, 0);
        }
    }
#pragma unroll
    for (int i = 0; i < 4; ++i) {
        int mb = m0 + wr + i * 16 + lg * 4;
#pragma unroll
        for (int j = 0; j < 4; ++j) {
            int n = n0 + wc + j * 16 + lr;
            float bvv = bias[n];
#pragma unroll
            for (int r = 0; r < 4; ++r)
                dst[(size_t)(mb + r) * 1024 + n] = (__bf16)((acc[i][j][r] + bvv) * sc);
        }
    }
}

// ---------------- final GEMM + GELU (64x128 tile) ----------------
__global__ __launch_bounds__(256) void gemm_out(const __bf16* __restrict__ A,
                                                const __bf16* __restrict__ Bt,
                                                const float* __restrict__ bias,
                                                float* __restrict__ dst) {
    __shared__ __bf16 As[64 * 64];
    __shared__ __bf16 Bs[128 * 64];
    int tid = threadIdx.x;
    int w = tid >> 6, lane = tid & 63, lg = lane >> 4, lr = lane & 15;
    int wr = (w >> 1) * 32, wc = (w & 1) * 64;
    int m0 = blockIdx.y * 64, n0 = blockIdx.x * 128;
    f32x4 acc[2][4] = {};
    for (int k0 = 0; k0 < 1024; k0 += 64) {
        __syncthreads();
        stage_tile<64>(A + (size_t)m0 * 1024 + k0, 1024, As, tid);
        stage_tile<128>(Bt + (size_t)n0 * 1024 + k0, 1024, Bs, tid);
        __syncthreads();
#pragma unroll
        for (int kk = 0; kk < 2; ++kk) {
            bf16x8 af[2], bfr[4];
#pragma unroll
            for (int t = 0; t < 2; ++t)
                af[t] = lds_frag(As, wr + t * 16 + lr, lg * 16 + kk * 64);
#pragma unroll
            for (int t = 0; t < 4; ++t)
                bfr[t] = lds_frag(Bs, wc + t * 16 + lr, lg * 16 + kk * 64);
#pragma unroll
            for (int i = 0; i < 2; ++i)
#pragma unroll
                for (int j = 0; j < 4; ++j)
                    acc[i][j] = __builtin_amdgcn_mfma_f32_16x16x32_bf16(
                        af[i], bfr[j], acc[i][j], 0, 0, 0);
        }
    }
#pragma unroll
    for (int i = 0; i < 2; ++i) {
        int mb = m0 + wr + i * 16 + lg * 4;
#pragma unroll
        for (int j = 0; j < 4; ++j) {
            int n = n0 + wc + j * 16 + lr;
            float bvv = bias[n];
#pragma unroll
            for (int r = 0; r < 4; ++r) {
                float v = acc[i][j][r] + bvv;
                float g = v / (1.f + exp2f(GELC * v));
                dst[(size_t)(mb + r) * 1024 + n] = g;
            }
        }
    }
}

// ---------------- flash attention: 32x32 MFMA, in-reg P, no LDS/barriers ----
// Block = 4 independent waves = 2 qtiles x 2 heads (L1 sharing of K/V + mask).
// Wave: 32 q rows, sweep kv in 64-tiles. T = K.Q^T via mfma_32x32x16 (swapped:
// row=kv, col=q=lane&31). Max-free softmax in log2 domain (Q pre-scaled,
// mask pre-scaled bf16). P redistributed across lane-halves with
// cvt_pk_bf16 + permlane32_swap -> PV B-fragments, O^T = V^T.P^T.
__global__ __launch_bounds__(256, 2) void attn_kernel(
    const __bf16* __restrict__ qs, const __bf16* __restrict__ ks,
    const __bf16* __restrict__ vT, const __bf16* __restrict__ mb0,
    const __bf16* __restrict__ mb1, __bf16* __restrict__ x) {
    int tid = threadIdx.x;
    int w = tid >> 6, l = tid & 63;
    int q31 = l & 31, hi = l >> 5;
    int b = blockIdx.x >> 3;
    int h = (blockIdx.x & 7) * 2 + (w >> 1);
    int qw = blockIdx.y * 64 + (w & 1) * 32;
    int bh = b * 16 + h;

    // Q fragments (B-operand): lane l holds Q[q=qw+q31][d = kk*16 + hi*8 + j]
    const __bf16* Qp = qs + ((size_t)b * 2048 + qw + q31) * 1024 + h * 64 + hi * 8;
    bf16x8 qf[4];
#pragma unroll
    for (int kk = 0; kk < 4; ++kk) qf[kk] = *(const bf16x8*)(Qp + kk * 16);

    const __bf16* Kp = ks + (size_t)b * 2048 * 1024 + h * 64 + hi * 8;
    const __bf16* Vp = vT + (size_t)bh * 64 * 2048 + hi * 8;
    const __bf16* mrow = (b ? mb1 : mb0) + ((size_t)(qw + q31)) * 2048 + hi * 4;

    // K prefetch for tile 0: A[m=kv=mt*32+q31][k = kk*16 + hi*8 + j]
    bf16x8 kf[2][4];
#pragma unroll
    for (int mt = 0; mt < 2; ++mt)
#pragma unroll
        for (int kk = 0; kk < 4; ++kk)
            kf[mt][kk] = *(const bf16x8*)(Kp + (size_t)(mt * 32 + q31) * 1024 + kk * 16);

    f32x16 O[2] = {};
    float l_acc = 0.f;

    for (int kv0 = 0; kv0 < 2048; kv0 += 64) {
        // mask loads: 4 bf16 (=8B) at kv = kv0 + mt*32 + g*8 + hi*4 + c
        uint2 ml[2][4];
#pragma unroll
        for (int mt = 0; mt < 2; ++mt)
#pragma unroll
            for (int g = 0; g < 4; ++g)
                ml[mt][g] = *(const uint2*)(mrow + kv0 + mt * 32 + g * 8);
        // V frags: A[m=e=mt*32+q31][k=kv = kv0 + kk*16 + hi*8 + j]
        bf16x8 vf[2][4];
#pragma unroll
        for (int mt = 0; mt < 2; ++mt)
#pragma unroll
            for (int kk = 0; kk < 4; ++kk)
                vf[mt][kk] = *(const bf16x8*)(Vp + (size_t)(mt * 32 + q31) * 2048 + kv0 + kk * 16);

        f32x16 T[2] = {};
        __builtin_amdgcn_s_setprio(1);
#pragma unroll
        for (int kk = 0; kk < 4; ++kk)
#pragma unroll
            for (int mt = 0; mt < 2; ++mt)
                T[mt] = __builtin_amdgcn_mfma_f32_32x32x16_bf16(kf[mt][kk], qf[kk], T[mt], 0, 0, 0);
        __builtin_amdgcn_s_setprio(0);

        if (kv0 + 64 < 2048) {
#pragma unroll
            for (int mt = 0; mt < 2; ++mt)
#pragma unroll
                for (int kk = 0; kk < 4; ++kk)
                    kf[mt][kk] = *(const bf16x8*)(Kp + (size_t)(kv0 + 64 + mt * 32 + q31) * 1024 + kk * 16);
        }

        // softmax (max-free, log2 domain): p = exp2(T + mask)
#pragma unroll
        for (int mt = 0; mt < 2; ++mt)
#pragma unroll
            for (int g = 0; g < 4; ++g) {
                float f0 = __uint_as_float(ml[mt][g].x << 16);
                float f1 = __uint_as_float(ml[mt][g].x & 0xffff0000u);
                float f2 = __uint_as_float(ml[mt][g].y << 16);
                float f3 = __uint_as_float(ml[mt][g].y & 0xffff0000u);
                float p0 = exp2f(T[mt][4 * g + 0] + f0);
                float p1 = exp2f(T[mt][4 * g + 1] + f1);
                float p2 = exp2f(T[mt][4 * g + 2] + f2);
                float p3 = exp2f(T[mt][4 * g + 3] + f3);
                l_acc += (p0 + p1) + (p2 + p3);
                T[mt][4 * g + 0] = p0; T[mt][4 * g + 1] = p1;
                T[mt][4 * g + 2] = p2; T[mt][4 * g + 3] = p3;
            }

        // P frags: frag[kk][j] = P[q=q31][kv = kk*16 + hi*8 + j]
        // x = pack(g=2kk&3), y = pack(g=2kk&3 + 1); swap lane-halves; frag=[x0,x1,y0,y1]
        bf16x8 pf[4];
#pragma unroll
        for (int kk = 0; kk < 4; ++kk) {
            int mt = kk >> 1;
            int gA = (2 * kk) & 3, gB = gA + 1;
            unsigned x0 = cvtpk(T[mt][4 * gA + 0], T[mt][4 * gA + 1]);
            unsigned x1 = cvtpk(T[mt][4 * gA + 2], T[mt][4 * gA + 3]);
            unsigned y0 = cvtpk(T[mt][4 * gB + 0], T[mt][4 * gB + 1]);
            unsigned y1 = cvtpk(T[mt][4 * gB + 2], T[mt][4 * gB + 3]);
            pswap(x0, y0);
            pswap(x1, y1);
            u32x4 packed; packed[0] = x0; packed[1] = x1; packed[2] = y0; packed[3] = y1;
            pf[kk] = __builtin_bit_cast(bf16x8, packed);
        }

        __builtin_amdgcn_s_setprio(1);
#pragma unroll
        for (int kk = 0; kk < 4; ++kk)
#pragma unroll
            for (int mt = 0; mt < 2; ++mt)
                O[mt] = __builtin_amdgcn_mfma_f32_32x32x16_bf16(vf[mt][kk], pf[kk], O[mt], 0, 0, 0);
        __builtin_amdgcn_s_setprio(0);
    }

    // row-sum lives split across lane and lane^32 (same q)
    l_acc += __shfl_xor(l_acc, 32, 64);
    float inv = 1.0f / l_acc;

    // O[mt][reg]: e = mt*32 + (reg&3) + 8*(reg>>2) + 4*hi, q = q31
    __bf16* xp = x + ((size_t)b * 2048 + qw + q31) * 1024 + h * 64 + hi * 4;
#pragma unroll
    for (int mt = 0; mt < 2; ++mt)
#pragma unroll
        for (int g = 0; g < 4; ++g) {
            bf16x4 o;
#pragma unroll
            for (int c = 0; c < 4; ++c) o[c] = (__bf16)(O[mt][4 * g + c] * inv);
            *(bf16x4*)(xp + mt * 32 + g * 8) = o;
        }
}

// ---------------- launch ----------------

extern "C" void kernel_launch(void* const* d_in, const int* in_sizes, int n_in,
                              void* d_out, int out_size, void* d_ws, size_t ws_size,
                              hipStream_t stream) {
    const float* q    = (const float*)d_in[0];
    const float* k    = (const float*)d_in[1];
    const float* v    = (const float*)d_in[2];
    const float* mask = (const float*)d_in[3];
    const float* Wq   = (const float*)d_in[4];
    const float* bq   = (const float*)d_in[5];
    const float* Wk   = (const float*)d_in[6];
    const float* bk   = (const float*)d_in[7];
    const float* Wv   = (const float*)d_in[8];
    const float* bv   = (const float*)d_in[9];
    const float* Wo   = (const float*)d_in[10];
    const float* bo   = (const float*)d_in[11];

    char* ws = (char*)d_ws;
    __bf16* qb  = (__bf16*)(ws + (0ull  << 20));   // reused as vT
    __bf16* kb  = (__bf16*)(ws + (8ull  << 20));   // reused as x
    __bf16* vb  = (__bf16*)(ws + (16ull << 20));   // reused as mb0 (8MB)
    __bf16* w3  = (__bf16*)(ws + (24ull << 20));   // 6 MB
    __bf16* wo  = (__bf16*)(ws + (30ull << 20));   // 2 MB
    __bf16* qhp = (__bf16*)(ws + (32ull << 20));
    __bf16* khp = (__bf16*)(ws + (40ull << 20));
    __bf16* vhp = (__bf16*)(ws + (48ull << 20));   // reused as mb1 (8MB)
    __bf16* vTp = qb;
    __bf16* xp  = kb;
    __bf16* mb0p = vb;
    __bf16* mb1p = vhp;

    cvt3_kernel<<<dim3(4096, 3), 256, 0, stream>>>(q, k, v, qb, kb, vb);
    pack_wqkv<<<dim3(16, 16, 3), 256, 0, stream>>>(Wq, Wk, Wv, w3);
    pack_wo<<<dim3(16, 16), 256, 0, stream>>>(Wo, wo);

    gemm_qkv<<<dim3(8, 32, 3), 256, 0, stream>>>(qb, kb, vb, w3, bq, bk, bv,
                                                 qhp, khp, vhp);
    vtrans<<<dim3(32, 32), 256, 0, stream>>>(vhp, vTp);
    mask_prep<<<dim3(4096, 2), 256, 0, stream>>>(mask, mb0p, mb1p);

    attn_kernel<<<dim3(16, 32), 256, 0, stream>>>(qhp, khp, vTp, mb0p, mb1p, xp);

    gemm_out<<<dim3(8, 64), 256, 0, stream>>>(xp, wo, bo, (float*)d_out);
}

// Round 5
// 185.936 us; speedup vs baseline: 1.4590x; 1.4590x over previous
//
#include <hip/hip_runtime.h>
#include <stdint.h>

// MultiHeadedAttention: B=2,S=2048,D=1024,H=16,HD=64
// R5: attn = LDS-staged K/V (coalesced global_load_lds, dbuf, XOR-swizzle)
// + 32x32x16 MFMA, 32 q/wave + in-register P (cvt_pk_bf16 + permlane32_swap,
// validated R4) + bf16*log2e mask w/ reg prefetch + max-free log2 softmax.
// GEMM/pack/cvt kernels unchanged from R3.
// Workspace: 0 qb/vT(reuse), 8 kb/x(reuse), 16 vb/mb0(reuse), 24 w3(6MB),
//            30 wo(2MB), 32 qh, 40 kh, 48 vh/mb1(reuse)  (total 56MB)

typedef __bf16 bf16x8 __attribute__((ext_vector_type(8)));
typedef __bf16 bf16x4 __attribute__((ext_vector_type(4)));
typedef float f32x4 __attribute__((ext_vector_type(4)));
typedef float f32x16 __attribute__((ext_vector_type(16)));
typedef unsigned u32x4 __attribute__((ext_vector_type(4)));

static constexpr float L2E  = 1.4426950408889634f;
static constexpr float QSCL = 0.18033688011112042f;   // 0.125 * log2(e)
static constexpr float GELC = -2.4554669595930157f;   // -1.702 * log2(e)

__device__ __forceinline__ void async_load16(const void* g, void* l) {
    __builtin_amdgcn_global_load_lds(
        (const __attribute__((address_space(1))) unsigned int*)(uintptr_t)g,
        (__attribute__((address_space(3))) unsigned int*)(unsigned int)(uintptr_t)l,
        16, 0, 0);
}

// Stage ROWS x 64-bf16 tile into LDS, phys = row*128 + (kb ^ ((row&7)<<4)).
template <int ROWS>
__device__ __forceinline__ void stage_tile(const __bf16* g, int ld, __bf16* lds, int tid) {
#pragma unroll
    for (int r = 0; r < ROWS / 32; ++r) {
        int p = r * 4096 + tid * 16;
        int row = p >> 7;
        int kbp = p & 127;
        int kbl = kbp ^ ((row & 7) << 4);
        async_load16((const char*)(g + (size_t)row * ld) + kbl,
                     (char*)lds + (p & ~1023));
    }
}

__device__ __forceinline__ bf16x8 lds_frag(const __bf16* base, int row, int kb) {
    return *(const bf16x8*)((const char*)base + (row << 7) + (kb ^ ((row & 7) << 4)));
}

__device__ __forceinline__ unsigned cvtpk(float a, float b) {
    unsigned d;
    asm("v_cvt_pk_bf16_f32 %0, %1, %2" : "=v"(d) : "v"(a), "v"(b));
    return d;
}
__device__ __forceinline__ void pswap(unsigned& a, unsigned& b) {
    asm("v_permlane32_swap_b32 %0, %1" : "+v"(a), "+v"(b));
}

// ---------------- prep kernels ----------------

__global__ __launch_bounds__(256) void cvt3_kernel(const float* __restrict__ q,
                                                   const float* __restrict__ k,
                                                   const float* __restrict__ v,
                                                   __bf16* __restrict__ qb,
                                                   __bf16* __restrict__ kb,
                                                   __bf16* __restrict__ vb) {
    int z = blockIdx.y;
    const float* src = z == 0 ? q : (z == 1 ? k : v);
    __bf16* dst = z == 0 ? qb : (z == 1 ? kb : vb);
    int i = blockIdx.x * 256 + threadIdx.x;
    f32x4 val = ((const f32x4*)src)[i];
    bf16x4 o;
    o[0] = (__bf16)val[0]; o[1] = (__bf16)val[1];
    o[2] = (__bf16)val[2]; o[3] = (__bf16)val[3];
    ((bf16x4*)dst)[i] = o;
}

// mask f32 -> bf16 pre-scaled by log2(e); split per batch
__global__ __launch_bounds__(256) void mask_prep(const float* __restrict__ m,
                                                 __bf16* __restrict__ mb0,
                                                 __bf16* __restrict__ mb1) {
    int b = blockIdx.y;
    const f32x4* src = (const f32x4*)(m + (size_t)b * 4194304);
    __bf16* dst = b ? mb1 : mb0;
    int i = blockIdx.x * 256 + threadIdx.x;
    f32x4 val = src[i];
    bf16x4 o;
    o[0] = (__bf16)(val[0] * L2E); o[1] = (__bf16)(val[1] * L2E);
    o[2] = (__bf16)(val[2] * L2E); o[3] = (__bf16)(val[3] * L2E);
    ((bf16x4*)dst)[i] = o;
}

__global__ __launch_bounds__(256) void pack_wqkv(const float* __restrict__ Wq,
                                                 const float* __restrict__ Wk,
                                                 const float* __restrict__ Wv,
                                                 __bf16* __restrict__ out) {
    __shared__ __bf16 T[64][72];
    int tid = threadIdx.x;
    int k0 = blockIdx.x * 64, h = blockIdx.y, z = blockIdx.z;
    const float* W = z == 0 ? Wq : (z == 1 ? Wk : Wv);
#pragma unroll
    for (int it = 0; it < 4; ++it) {
        int idx = it * 1024 + tid * 4;
        int r = idx >> 6, e = idx & 63;
        f32x4 val = *(const f32x4*)(W + ((size_t)h * 1024 + k0 + r) * 64 + e);
#pragma unroll
        for (int j = 0; j < 4; ++j) T[r][e + j] = (__bf16)val[j];
    }
    __syncthreads();
    int e2 = tid >> 2, kc = (tid & 3) * 16;
    bf16x8 o0, o1;
#pragma unroll
    for (int i = 0; i < 8; ++i) { o0[i] = T[kc + i][e2]; o1[i] = T[kc + 8 + i][e2]; }
    __bf16* dst = out + ((size_t)z << 20) + (size_t)(h * 64 + e2) * 1024 + k0 + kc;
    *(bf16x8*)dst = o0;
    *(bf16x8*)(dst + 8) = o1;
}

__global__ __launch_bounds__(256) void pack_wo(const float* __restrict__ Wo,
                                               __bf16* __restrict__ out) {
    __shared__ __bf16 T[64][72];
    int tid = threadIdx.x;
    int k0 = blockIdx.x * 64, n0 = blockIdx.y * 64;
#pragma unroll
    for (int it = 0; it < 4; ++it) {
        int idx = it * 1024 + tid * 4;
        int r = idx >> 6, e = idx & 63;
        f32x4 val = *(const f32x4*)(Wo + (size_t)(k0 + r) * 1024 + n0 + e);
#pragma unroll
        for (int j = 0; j < 4; ++j) T[r][e + j] = (__bf16)val[j];
    }
    __syncthreads();
    int e2 = tid >> 2, kc = (tid & 3) * 16;
    bf16x8 o0, o1;
#pragma unroll
    for (int i = 0; i < 8; ++i) { o0[i] = T[kc + i][e2]; o1[i] = T[kc + 8 + i][e2]; }
    __bf16* dst = out + (size_t)(n0 + e2) * 1024 + k0 + kc;
    *(bf16x8*)dst = o0;
    *(bf16x8*)(dst + 8) = o1;
}

// vh [B,S,D] bf16 -> vT [B,H,HD,S] bf16
__global__ __launch_bounds__(256) void vtrans(const __bf16* __restrict__ vh,
                                              __bf16* __restrict__ vT) {
    __shared__ __bf16 T[64][72];
    int tid = threadIdx.x;
    int s0 = blockIdx.x * 64, bh = blockIdx.y, b = bh >> 4, h = bh & 15;
#pragma unroll
    for (int it = 0; it < 2; ++it) {
        int idx = it * 2048 + tid * 8;
        int r = idx >> 6, e0 = idx & 63;
        bf16x8 val = *(const bf16x8*)(vh + ((size_t)b * 2048 + s0 + r) * 1024 + h * 64 + e0);
#pragma unroll
        for (int j = 0; j < 8; ++j) T[r][e0 + j] = val[j];
    }
    __syncthreads();
    int e = tid >> 2, sc = (tid & 3) * 16;
    bf16x8 o0, o1;
#pragma unroll
    for (int i = 0; i < 8; ++i) { o0[i] = T[sc + i][e]; o1[i] = T[sc + 8 + i][e]; }
    __bf16* dst = vT + ((size_t)bh * 64 + e) * 2048 + s0 + sc;
    *(bf16x8*)dst = o0;
    *(bf16x8*)(dst + 8) = o1;
}

// ---------------- fused QKV GEMM ----------------
__global__ __launch_bounds__(256) void gemm_qkv(
    const __bf16* __restrict__ qb, const __bf16* __restrict__ kb,
    const __bf16* __restrict__ vb, const __bf16* __restrict__ w3,
    const float* __restrict__ bq, const float* __restrict__ bk,
    const float* __restrict__ bv,
    __bf16* __restrict__ qo, __bf16* __restrict__ ko, __bf16* __restrict__ vo) {
    __shared__ __bf16 As[128 * 64];
    __shared__ __bf16 Bs[128 * 64];
    int z = blockIdx.z;
    const __bf16* A = z == 0 ? qb : (z == 1 ? kb : vb);
    const __bf16* Bt = w3 + ((size_t)z << 20);
    const float* bias = z == 0 ? bq : (z == 1 ? bk : bv);
    __bf16* dst = z == 0 ? qo : (z == 1 ? ko : vo);
    float sc = z == 0 ? QSCL : 1.0f;

    int tid = threadIdx.x;
    int w = tid >> 6, lane = tid & 63, lg = lane >> 4, lr = lane & 15;
    int wr = (w >> 1) * 64, wc = (w & 1) * 64;
    int m0 = blockIdx.y * 128, n0 = blockIdx.x * 128;
    f32x4 acc[4][4] = {};
    for (int k0 = 0; k0 < 1024; k0 += 64) {
        __syncthreads();
        stage_tile<128>(A + (size_t)m0 * 1024 + k0, 1024, As, tid);
        stage_tile<128>(Bt + (size_t)n0 * 1024 + k0, 1024, Bs, tid);
        __syncthreads();
#pragma unroll
        for (int kk = 0; kk < 2; ++kk) {
            bf16x8 af[4], bfr[4];
#pragma unroll
            for (int t = 0; t < 4; ++t) {
                af[t] = lds_frag(As, wr + t * 16 + lr, lg * 16 + kk * 64);
                bfr[t] = lds_frag(Bs, wc + t * 16 + lr, lg * 16 + kk * 64);
            }
#pragma unroll
            for (int i = 0; i < 4; ++i)
#pragma unroll
                for (int j = 0; j < 4; ++j)
                    acc[i][j] = __builtin_amdgcn_mfma_f32_16x16x32_bf16(
                        af[i], bfr[j], acc[i][j], 0, 0, 0);
        }
    }
#pragma unroll
    for (int i = 0; i < 4; ++i) {
        int mb = m0 + wr + i * 16 + lg * 4;
#pragma unroll
        for (int j = 0; j < 4; ++j) {
            int n = n0 + wc + j * 16 + lr;
            float bvv = bias[n];
#pragma unroll
            for (int r = 0; r < 4; ++r)
                dst[(size_t)(mb + r) * 1024 + n] = (__bf16)((acc[i][j][r] + bvv) * sc);
        }
    }
}

// ---------------- final GEMM + GELU (64x128 tile) ----------------
__global__ __launch_bounds__(256) void gemm_out(const __bf16* __restrict__ A,
                                                const __bf16* __restrict__ Bt,
                                                const float* __restrict__ bias,
                                                float* __restrict__ dst) {
    __shared__ __bf16 As[64 * 64];
    __shared__ __bf16 Bs[128 * 64];
    int tid = threadIdx.x;
    int w = tid >> 6, lane = tid & 63, lg = lane >> 4, lr = lane & 15;
    int wr = (w >> 1) * 32, wc = (w & 1) * 64;
    int m0 = blockIdx.y * 64, n0 = blockIdx.x * 128;
    f32x4 acc[2][4] = {};
    for (int k0 = 0; k0 < 1024; k0 += 64) {
        __syncthreads();
        stage_tile<64>(A + (size_t)m0 * 1024 + k0, 1024, As, tid);
        stage_tile<128>(Bt + (size_t)n0 * 1024 + k0, 1024, Bs, tid);
        __syncthreads();
#pragma unroll
        for (int kk = 0; kk < 2; ++kk) {
            bf16x8 af[2], bfr[4];
#pragma unroll
            for (int t = 0; t < 2; ++t)
                af[t] = lds_frag(As, wr + t * 16 + lr, lg * 16 + kk * 64);
#pragma unroll
            for (int t = 0; t < 4; ++t)
                bfr[t] = lds_frag(Bs, wc + t * 16 + lr, lg * 16 + kk * 64);
#pragma unroll
            for (int i = 0; i < 2; ++i)
#pragma unroll
                for (int j = 0; j < 4; ++j)
                    acc[i][j] = __builtin_amdgcn_mfma_f32_16x16x32_bf16(
                        af[i], bfr[j], acc[i][j], 0, 0, 0);
        }
    }
#pragma unroll
    for (int i = 0; i < 2; ++i) {
        int mb = m0 + wr + i * 16 + lg * 4;
#pragma unroll
        for (int j = 0; j < 4; ++j) {
            int n = n0 + wc + j * 16 + lr;
            float bvv = bias[n];
#pragma unroll
            for (int r = 0; r < 4; ++r) {
                float v = acc[i][j][r] + bvv;
                float g = v / (1.f + exp2f(GELC * v));
                dst[(size_t)(mb + r) * 1024 + n] = g;
            }
        }
    }
}

// ---------------- flash attention: LDS K/V + 32x32 MFMA + in-reg P ----------
// grid (S/128, B*H); 4 waves x 32 q-rows, all sharing (b,h) K/V tiles.
// K [64 kv][64 d] and V^T [64 e][64 kv] double-buffered in LDS (swizzled),
// staged with global_load_lds. Swapped QK^T: T[mt] rows kv, cols q=lane&31.
// Max-free log2-domain softmax (Q pre-scaled, mask bf16 pre-scaled), P packed
// in-register via cvt_pk_bf16 + permlane32_swap (R4-validated mapping).
__global__ __launch_bounds__(256) void attn_kernel(
    const __bf16* __restrict__ qs, const __bf16* __restrict__ ks,
    const __bf16* __restrict__ vT, const __bf16* __restrict__ mb0,
    const __bf16* __restrict__ mb1, __bf16* __restrict__ x) {
    __shared__ __bf16 Ks[2][64 * 64];
    __shared__ __bf16 Vs[2][64 * 64];
    int tid = threadIdx.x;
    int w = tid >> 6, l = tid & 63;
    int q31 = l & 31, hi = l >> 5;
    int bh = blockIdx.y, b = bh >> 4, h = bh & 15;
    int qw = blockIdx.x * 128 + w * 32;

    // Q fragments (B-operand): lane holds Q[q=qw+q31][d = kk*16 + hi*8 + j]
    const __bf16* Qp = qs + ((size_t)b * 2048 + qw + q31) * 1024 + h * 64 + hi * 8;
    bf16x8 qf[4];
#pragma unroll
    for (int kk = 0; kk < 4; ++kk) qf[kk] = *(const bf16x8*)(Qp + kk * 16);

    const __bf16* Kb = ks + (size_t)b * 2048 * 1024 + h * 64;
    const __bf16* Vb = vT + (size_t)bh * 64 * 2048;
    const __bf16* mrow = (b ? mb1 : mb0) + (size_t)(qw + q31) * 2048 + hi * 4;

    f32x16 O[2] = {};
    float l_acc = 0.f;

    stage_tile<64>(Kb, 1024, Ks[0], tid);
    stage_tile<64>(Vb, 2048, Vs[0], tid);
    uint2 ml[2][4], mln[2][4];
#pragma unroll
    for (int mt = 0; mt < 2; ++mt)
#pragma unroll
        for (int g = 0; g < 4; ++g)
            ml[mt][g] = *(const uint2*)(mrow + mt * 32 + g * 8);

    for (int kv0 = 0; kv0 < 2048; kv0 += 64) {
        int buf = (kv0 >> 6) & 1;
        __syncthreads();   // buf staged (barrier drains vmcnt); buf^1 free
        if (kv0 + 64 < 2048) {
            stage_tile<64>(Kb + (size_t)(kv0 + 64) * 1024, 1024, Ks[buf ^ 1], tid);
            stage_tile<64>(Vb + (kv0 + 64), 2048, Vs[buf ^ 1], tid);
#pragma unroll
            for (int mt = 0; mt < 2; ++mt)
#pragma unroll
                for (int g = 0; g < 4; ++g)
                    mln[mt][g] = *(const uint2*)(mrow + kv0 + 64 + mt * 32 + g * 8);
        }
        // K frags from LDS: A[kv = mt*32 + q31][d = kk*16 + hi*8 ..+8]
        bf16x8 kf[2][4], vf[2][4];
#pragma unroll
        for (int mt = 0; mt < 2; ++mt)
#pragma unroll
            for (int kk = 0; kk < 4; ++kk) {
                kf[mt][kk] = lds_frag(Ks[buf], mt * 32 + q31, kk * 32 + hi * 16);
                vf[mt][kk] = lds_frag(Vs[buf], mt * 32 + q31, kk * 32 + hi * 16);
            }
        f32x16 T[2] = {};
        __builtin_amdgcn_s_setprio(1);
#pragma unroll
        for (int kk = 0; kk < 4; ++kk)
#pragma unroll
            for (int mt = 0; mt < 2; ++mt)
                T[mt] = __builtin_amdgcn_mfma_f32_32x32x16_bf16(kf[mt][kk], qf[kk], T[mt], 0, 0, 0);
        __builtin_amdgcn_s_setprio(0);

        // softmax (max-free, log2 domain): p = exp2(T + mask)
#pragma unroll
        for (int mt = 0; mt < 2; ++mt)
#pragma unroll
            for (int g = 0; g < 4; ++g) {
                float f0 = __uint_as_float(ml[mt][g].x << 16);
                float f1 = __uint_as_float(ml[mt][g].x & 0xffff0000u);
                float f2 = __uint_as_float(ml[mt][g].y << 16);
                float f3 = __uint_as_float(ml[mt][g].y & 0xffff0000u);
                float p0 = exp2f(T[mt][4 * g + 0] + f0);
                float p1 = exp2f(T[mt][4 * g + 1] + f1);
                float p2 = exp2f(T[mt][4 * g + 2] + f2);
                float p3 = exp2f(T[mt][4 * g + 3] + f3);
                l_acc += (p0 + p1) + (p2 + p3);
                T[mt][4 * g + 0] = p0; T[mt][4 * g + 1] = p1;
                T[mt][4 * g + 2] = p2; T[mt][4 * g + 3] = p3;
            }
#pragma unroll
        for (int mt = 0; mt < 2; ++mt)
#pragma unroll
            for (int g = 0; g < 4; ++g) ml[mt][g] = mln[mt][g];

        // P frags in-register (R4-validated): pf[kk][j] = P[q=q31][kk*16+hi*8+j]
        bf16x8 pf[4];
#pragma unroll
        for (int kk = 0; kk < 4; ++kk) {
            int mt = kk >> 1;
            int gA = (2 * kk) & 3, gB = gA + 1;
            unsigned x0 = cvtpk(T[mt][4 * gA + 0], T[mt][4 * gA + 1]);
            unsigned x1 = cvtpk(T[mt][4 * gA + 2], T[mt][4 * gA + 3]);
            unsigned y0 = cvtpk(T[mt][4 * gB + 0], T[mt][4 * gB + 1]);
            unsigned y1 = cvtpk(T[mt][4 * gB + 2], T[mt][4 * gB + 3]);
            pswap(x0, y0);
            pswap(x1, y1);
            u32x4 packed; packed[0] = x0; packed[1] = x1; packed[2] = y0; packed[3] = y1;
            pf[kk] = __builtin_bit_cast(bf16x8, packed);
        }

        __builtin_amdgcn_s_setprio(1);
#pragma unroll
        for (int kk = 0; kk < 4; ++kk)
#pragma unroll
            for (int mt = 0; mt < 2; ++mt)
                O[mt] = __builtin_amdgcn_mfma_f32_32x32x16_bf16(vf[mt][kk], pf[kk], O[mt], 0, 0, 0);
        __builtin_amdgcn_s_setprio(0);
    }

    // full row-sum = lane + lane^32
    l_acc += __shfl_xor(l_acc, 32, 64);
    float inv = 1.0f / l_acc;

    // O[mt][r]: e = mt*32 + (r&3) + 8*(r>>2) + 4*hi, q = q31
    __bf16* xp = x + ((size_t)b * 2048 + qw + q31) * 1024 + h * 64 + hi * 4;
#pragma unroll
    for (int mt = 0; mt < 2; ++mt)
#pragma unroll
        for (int g = 0; g < 4; ++g) {
            bf16x4 o;
#pragma unroll
            for (int c = 0; c < 4; ++c) o[c] = (__bf16)(O[mt][4 * g + c] * inv);
            *(bf16x4*)(xp + mt * 32 + g * 8) = o;
        }
}

// ---------------- launch ----------------

extern "C" void kernel_launch(void* const* d_in, const int* in_sizes, int n_in,
                              void* d_out, int out_size, void* d_ws, size_t ws_size,
                              hipStream_t stream) {
    const float* q    = (const float*)d_in[0];
    const float* k    = (const float*)d_in[1];
    const float* v    = (const float*)d_in[2];
    const float* mask = (const float*)d_in[3];
    const float* Wq   = (const float*)d_in[4];
    const float* bq   = (const float*)d_in[5];
    const float* Wk   = (const float*)d_in[6];
    const float* bk   = (const float*)d_in[7];
    const float* Wv   = (const float*)d_in[8];
    const float* bv   = (const float*)d_in[9];
    const float* Wo   = (const float*)d_in[10];
    const float* bo   = (const float*)d_in[11];

    char* ws = (char*)d_ws;
    __bf16* qb  = (__bf16*)(ws + (0ull  << 20));   // reused as vT
    __bf16* kb  = (__bf16*)(ws + (8ull  << 20));   // reused as x
    __bf16* vb  = (__bf16*)(ws + (16ull << 20));   // reused as mb0
    __bf16* w3  = (__bf16*)(ws + (24ull << 20));   // 6 MB
    __bf16* wo  = (__bf16*)(ws + (30ull << 20));   // 2 MB
    __bf16* qhp = (__bf16*)(ws + (32ull << 20));
    __bf16* khp = (__bf16*)(ws + (40ull << 20));
    __bf16* vhp = (__bf16*)(ws + (48ull << 20));   // reused as mb1
    __bf16* vTp = qb;
    __bf16* xp  = kb;
    __bf16* mb0p = vb;
    __bf16* mb1p = vhp;

    cvt3_kernel<<<dim3(4096, 3), 256, 0, stream>>>(q, k, v, qb, kb, vb);
    pack_wqkv<<<dim3(16, 16, 3), 256, 0, stream>>>(Wq, Wk, Wv, w3);
    pack_wo<<<dim3(16, 16), 256, 0, stream>>>(Wo, wo);

    gemm_qkv<<<dim3(8, 32, 3), 256, 0, stream>>>(qb, kb, vb, w3, bq, bk, bv,
                                                 qhp, khp, vhp);
    vtrans<<<dim3(32, 32), 256, 0, stream>>>(vhp, vTp);
    mask_prep<<<dim3(4096, 2), 256, 0, stream>>>(mask, mb0p, mb1p);

    attn_kernel<<<dim3(16, 32), 256, 0, stream>>>(qhp, khp, vTp, mb0p, mb1p, xp);

    gemm_out<<<dim3(8, 64), 256, 0, stream>>>(xp, wo, bo, (float*)d_out);
}